// Round 12
// baseline (272.947 us; speedup 1.0000x reference)
//
#include <hip/hip_runtime.h>

#define HH 16
#define RED_VALS 34   // 16 top(g.p) + 16 (y.p) + cur + gg
#define OUTBLK 2048

// Pure-TLP reduction: one wave owns one (row, 64-chunk span) partial dot.
// 2 vector loads per wave iteration, VGPR ~20 -> near-full occupancy;
// concurrency from wave count, not per-thread ILP (which 9 variants showed
// caps at ~3 TB/s due to regalloc batching/spill).
// grid = (ngrp, 9): blockIdx.y<8 -> rows 4*by+wave (0..15 = g.p, 16..31 = y.p);
// blockIdx.y==8 -> wave0: y_h.g_h (cur), wave1: g_h.g_h (gg).
__global__ __launch_bounds__(256) void lbfgs_reduce_tlp(
    const float* __restrict__ p, const float* __restrict__ y,
    const float* __restrict__ g, const int* __restrict__ idxp,
    float* __restrict__ partials, int ngrp, int n) {
  const int grp = blockIdx.x;
  const int wave = threadIdx.x >> 6, lane = threadIdx.x & 63;
  const int nchunk = n >> 2;
  const int is = idxp[0];
  const int hidx = ((is - 1) % HH + HH) % HH;

  float v = 0.f;
  int outj = -1;

  if (blockIdx.y < 8) {
    const int r = blockIdx.y * 4 + wave;   // 0..31
    const float* __restrict__ row =
        (r < HH) ? (g + (size_t)r * n) : (y + (size_t)(r - HH) * n);
    const float4* __restrict__ row4 = reinterpret_cast<const float4*>(row);
    const float4* __restrict__ p4 = reinterpret_cast<const float4*>(p);
    for (int c = grp * 64 + lane; c < nchunk; c += ngrp * 64) {
      float4 rv = row4[c];
      float4 pv = p4[c];
      v += rv.x * pv.x + rv.y * pv.y + rv.z * pv.z + rv.w * pv.w;
    }
    if (grp == 0) {  // scalar tail (n % 4 != 0)
      for (int e = (nchunk << 2) + lane; e < n; e += 64)
        v += row[e] * p[e];
    }
    outj = r;
  } else if (wave < 2) {
    const float* __restrict__ gh = g + (size_t)hidx * n;
    const float* __restrict__ oth = (wave == 0) ? (y + (size_t)hidx * n) : gh;
    const float4* __restrict__ gh4 = reinterpret_cast<const float4*>(gh);
    const float4* __restrict__ ot4 = reinterpret_cast<const float4*>(oth);
    for (int c = grp * 64 + lane; c < nchunk; c += ngrp * 64) {
      float4 a = gh4[c];
      float4 b = ot4[c];
      v += a.x * b.x + a.y * b.y + a.z * b.z + a.w * b.w;
    }
    if (grp == 0) {
      for (int e = (nchunk << 2) + lane; e < n; e += 64)
        v += gh[e] * oth[e];
    }
    outj = 32 + wave;
  }

  // wave(64) shuffle reduce; lane 0 writes the partial
#pragma unroll
  for (int off = 32; off > 0; off >>= 1) v += __shfl_down(v, off);
  if (lane == 0 && outj >= 0)
    partials[(size_t)outj * ngrp + grp] = v;  // [RED_VALS][ngrp] column-major
}

// Stage 2: 34 blocks, block j sums partials[j][0..ngrp) (contiguous,
// coalesced) -> sums[j].
__global__ __launch_bounds__(256) void lbfgs_stage2(
    const float* __restrict__ partials, int nblk, float* __restrict__ sums) {
  const int j = blockIdx.x;
  float v = 0.f;
  for (int b = threadIdx.x; b < nblk; b += 256)
    v += partials[(size_t)j * nblk + b];
#pragma unroll
  for (int off = 32; off > 0; off >>= 1) v += __shfl_down(v, off);
  __shared__ float red[4];
  const int wave = threadIdx.x >> 6, lane = threadIdx.x & 63;
  if (lane == 0) red[wave] = v;
  __syncthreads();
  if (threadIdx.x == 0)
    sums[j] = red[0] + red[1] + red[2] + red[3];
}

__global__ __launch_bounds__(256) void lbfgs_solve(
    const float* __restrict__ sums_g,
    const float* __restrict__ Lmat, const float* __restrict__ diag,
    const float* __restrict__ sinner, const int* __restrict__ idxp,
    float* __restrict__ coeff) {
  __shared__ float sums[RED_VALS];
  if (threadIdx.x < RED_VALS) sums[threadIdx.x] = sums_g[threadIdx.x];
  __syncthreads();

  __shared__ float Lsh[HH][HH];
  __shared__ float dd[HH], sqd[HH];
  __shared__ float Jsq[HH][HH];
  __shared__ float gamma_s;
  __shared__ float x[2 * HH];
  {
    int i = threadIdx.x >> 4, j = threadIdx.x & 15;
    if (threadIdx.x < 256) Lsh[i][j] = Lmat[i * HH + j];
  }
  if (threadIdx.x < HH) {
    float dv = diag[threadIdx.x];
    float ddv = (dv == 0.f) ? 1.f : dv;
    dd[threadIdx.x] = ddv;
    sqd[threadIdx.x] = sqrtf(ddv);
  }
  if (threadIdx.x == 0) {
    float cur = sums[32], gg = sums[33];
    gamma_s = (cur > 0.f) ? (gg / cur) : 1.f;
  }
  __syncthreads();
  {
    int i = threadIdx.x >> 4, j = threadIdx.x & 15;
    float v = gamma_s * sinner[i * HH + j];
#pragma unroll
    for (int k = 0; k < HH; ++k) v += Lsh[i][k] * Lsh[j][k] / dd[k];
    Jsq[i][j] = v;
  }
  __syncthreads();
  if (threadIdx.x == 0) {
    // in-place lower Cholesky of Jsq (16x16, serial — tiny)
    for (int c = 0; c < HH; ++c) {
      float s = Jsq[c][c];
      for (int k = 0; k < c; ++k) s -= Jsq[c][k] * Jsq[c][k];
      float dv = sqrtf(s);
      Jsq[c][c] = dv;
      float inv = 1.f / dv;
      for (int r = c + 1; r < HH; ++r) {
        float s2 = Jsq[r][c];
        for (int k = 0; k < c; ++k) s2 -= Jsq[r][k] * Jsq[c][k];
        Jsq[r][c] = s2 * inv;
      }
    }
    const int is = idxp[0];
    const int sh = (is <= HH) ? 0 : (is % HH);
    const float gamma = gamma_s;
    // build rolled descent vector
    for (int k = 0; k < HH; ++k) {
      x[k]      = sums[(k + sh) & (HH - 1)];
      x[HH + k] = gamma * sums[HH + ((k + sh) & (HH - 1))];
    }
    // forward solve: low_tri = [[diag(sqd), 0], [-L/sqd_col, J]]
    for (int i = 0; i < HH; ++i) x[i] /= sqd[i];
    for (int i = 0; i < HH; ++i) {
      float s = x[HH + i];
      for (int j = 0; j < HH; ++j) s += (Lsh[i][j] / sqd[j]) * x[j];
      for (int j = 0; j < i; ++j) s -= Jsq[i][j] * x[HH + j];
      x[HH + i] = s / Jsq[i][i];
    }
    // backward solve: upper = low^T with top h rows negated
    for (int i = HH - 1; i >= 0; --i) {
      float s = x[HH + i];
      for (int j = i + 1; j < HH; ++j) s -= Jsq[j][i] * x[HH + j];
      x[HH + i] = s / Jsq[i][i];
    }
    for (int i = 0; i < HH; ++i) {
      float s = x[i];
      for (int j = 0; j < HH; ++j) s -= (Lsh[j][i] / sqd[i]) * x[HH + j];
      x[i] = s / (-sqd[i]);
    }
    // un-roll and emit coefficients (beta pre-scaled by gamma)
    coeff[0] = gamma;
    for (int k = 0; k < HH; ++k) {
      coeff[1 + k]      = x[(k - sh + HH) & (HH - 1)];
      coeff[1 + HH + k] = gamma * x[HH + ((k - sh + HH) & (HH - 1))];
    }
  }
}

// Plain ascending grid-stride (proven fastest streaming form).
__global__ __launch_bounds__(256) void lbfgs_output(
    const float* __restrict__ p, const float* __restrict__ y,
    const float* __restrict__ g, const float* __restrict__ coeff,
    float* __restrict__ out, int n) {
  const float gamma = coeff[0];
  float a[HH], b[HH];
#pragma unroll
  for (int i = 0; i < HH; ++i) {
    a[i] = coeff[1 + i];
    b[i] = coeff[1 + HH + i];
  }
  const int tid = blockIdx.x * blockDim.x + threadIdx.x;
  const int nth = gridDim.x * blockDim.x;
  const int nchunk = n >> 2;
  const float4* __restrict__ p4 = reinterpret_cast<const float4*>(p);
  float4* __restrict__ out4 = reinterpret_cast<float4*>(out);
  for (int c = tid; c < nchunk; c += nth) {
    float4 pv = p4[c];
    float ox = gamma * pv.x, oy = gamma * pv.y;
    float oz = gamma * pv.z, ow = gamma * pv.w;
#pragma unroll
    for (int i = 0; i < HH; ++i) {
      const float4 gv = reinterpret_cast<const float4*>(g + (size_t)i * n)[c];
      const float4 yv = reinterpret_cast<const float4*>(y + (size_t)i * n)[c];
      ox -= a[i] * gv.x + b[i] * yv.x;
      oy -= a[i] * gv.y + b[i] * yv.y;
      oz -= a[i] * gv.z + b[i] * yv.z;
      ow -= a[i] * gv.w + b[i] * yv.w;
    }
    out4[c] = make_float4(ox, oy, oz, ow);
  }
  for (int c = (nchunk << 2) + tid; c < n; c += nth) {
    float pv = p[c];
    float o = gamma * pv;
#pragma unroll
    for (int i = 0; i < HH; ++i)
      o -= a[i] * g[(size_t)i * n + c] + b[i] * y[(size_t)i * n + c];
    out[c] = o;
  }
}

extern "C" void kernel_launch(void* const* d_in, const int* in_sizes, int n_in,
                              void* d_out, int out_size, void* d_ws, size_t ws_size,
                              hipStream_t stream) {
  const float* p      = (const float*)d_in[0];
  const float* y      = (const float*)d_in[1];
  const float* g      = (const float*)d_in[2];
  const float* Lmat   = (const float*)d_in[3];
  const float* diag   = (const float*)d_in[4];
  const float* sinner = (const float*)d_in[5];
  const int*   idxp   = (const int*)d_in[6];
  float* out = (float*)d_out;
  float* wsf = (float*)d_ws;
  const int n = in_sizes[0];

  const int nchunk = n >> 2;
  int ngrp = (nchunk + 63) / 64;          // one 64-chunk span per wave
  {
    long avail = (long)(ws_size / sizeof(float)) - RED_VALS - 64;
    long cap = avail / RED_VALS;
    if (cap < 1) cap = 1;
    if (ngrp > cap) ngrp = (int)cap;      // waves loop if ws-limited
  }
  float* partials = wsf;
  float* sums     = wsf + (size_t)RED_VALS * ngrp;
  float* coeff    = sums + RED_VALS;

  lbfgs_reduce_tlp<<<dim3(ngrp, 9), dim3(256), 0, stream>>>(
      p, y, g, idxp, partials, ngrp, n);
  lbfgs_stage2<<<dim3(RED_VALS), dim3(256), 0, stream>>>(partials, ngrp, sums);
  lbfgs_solve<<<dim3(1), dim3(256), 0, stream>>>(sums, Lmat, diag,
                                                 sinner, idxp, coeff);
  lbfgs_output<<<dim3(OUTBLK), dim3(256), 0, stream>>>(p, y, g, coeff, out, n);
}

// Round 13
// 232.638 us; speedup vs baseline: 1.1733x; 1.1733x over previous
//
#include <hip/hip_runtime.h>

#define HH 16
#define RED_VALS 34   // 16 top(g.p) + 16 (y.p) + cur + gg
#define OUTBLK 2048

// TLP + 4x chunk-unroll reduction. One wave = one row; per iteration it
// processes a 256-chunk "quad": 8 independent float4 loads (4 row + 4 p),
// elementwise-accumulated into ONE carried float4 (horizontal reduce
// deferred to epilogue). VGPR budget ~55 (<=64 -> 8 waves/SIMD), giving
// ~4KB outstanding loads/CU vs R12's 1KB — the Little's-law fix for the
// 150us plateau (R12: 2 loads in flight/wave at 80% occ = 3.5 TB/s).
// grid = (ngrp, 9): by<8 -> row r=by*4+wave (0..15 g.p, 16..31 y.p);
// by==8 -> wave0: y_h.g_h (cur), wave1: g_h.g_h (gg).
__global__ __launch_bounds__(256) void lbfgs_reduce_tlp4(
    const float* __restrict__ p, const float* __restrict__ y,
    const float* __restrict__ g, const int* __restrict__ idxp,
    float* __restrict__ partials, int ngrp, int n) {
  const int grp = blockIdx.x;
  const int wave = threadIdx.x >> 6, lane = threadIdx.x & 63;
  const int nchunk = n >> 2;
  const int nq = nchunk >> 8;            // full 256-chunk quads
  const int is = idxp[0];
  const int hidx = ((is - 1) % HH + HH) % HH;

  float ax = 0.f, ay = 0.f, az = 0.f, aw = 0.f;
  int outj = -1;
  const float4* __restrict__ p4 = reinterpret_cast<const float4*>(p);

  if (blockIdx.y < 8) {
    const int r = blockIdx.y * 4 + wave;   // 0..31
    const float* __restrict__ row =
        (r < HH) ? (g + (size_t)r * n) : (y + (size_t)(r - HH) * n);
    const float4* __restrict__ row4 = reinterpret_cast<const float4*>(row);
    for (int q = grp; q < nq; q += ngrp) {
      const int b = (q << 8) + lane;
      float4 r0 = row4[b      ], r1 = row4[b +  64];
      float4 r2 = row4[b + 128], r3 = row4[b + 192];
      float4 q0 = p4[b      ], q1 = p4[b +  64];
      float4 q2 = p4[b + 128], q3 = p4[b + 192];
      ax += r0.x * q0.x; ay += r0.y * q0.y; az += r0.z * q0.z; aw += r0.w * q0.w;
      ax += r1.x * q1.x; ay += r1.y * q1.y; az += r1.z * q1.z; aw += r1.w * q1.w;
      ax += r2.x * q2.x; ay += r2.y * q2.y; az += r2.z * q2.z; aw += r2.w * q2.w;
      ax += r3.x * q3.x; ay += r3.y * q3.y; az += r3.z * q3.z; aw += r3.w * q3.w;
    }
    if (grp == 0) {
      // leftover chunks beyond the last full quad
      for (int c = (nq << 8) + lane; c < nchunk; c += 64) {
        float4 rv = row4[c], pv = p4[c];
        ax += rv.x * pv.x; ay += rv.y * pv.y;
        az += rv.z * pv.z; aw += rv.w * pv.w;
      }
      // scalar tail (n % 4 != 0)
      for (int e = (nchunk << 2) + lane; e < n; e += 64)
        ax += row[e] * p[e];
    }
    outj = r;
  } else if (wave < 2) {
    const float* __restrict__ gh = g + (size_t)hidx * n;
    const float* __restrict__ oth = (wave == 0) ? (y + (size_t)hidx * n) : gh;
    const float4* __restrict__ gh4 = reinterpret_cast<const float4*>(gh);
    const float4* __restrict__ ot4 = reinterpret_cast<const float4*>(oth);
    for (int q = grp; q < nq; q += ngrp) {
      const int b = (q << 8) + lane;
      float4 a0 = gh4[b      ], a1 = gh4[b +  64];
      float4 a2 = gh4[b + 128], a3 = gh4[b + 192];
      float4 b0 = ot4[b      ], b1 = ot4[b +  64];
      float4 b2 = ot4[b + 128], b3 = ot4[b + 192];
      ax += a0.x * b0.x; ay += a0.y * b0.y; az += a0.z * b0.z; aw += a0.w * b0.w;
      ax += a1.x * b1.x; ay += a1.y * b1.y; az += a1.z * b1.z; aw += a1.w * b1.w;
      ax += a2.x * b2.x; ay += a2.y * b2.y; az += a2.z * b2.z; aw += a2.w * b2.w;
      ax += a3.x * b3.x; ay += a3.y * b3.y; az += a3.z * b3.z; aw += a3.w * b3.w;
    }
    if (grp == 0) {
      for (int c = (nq << 8) + lane; c < nchunk; c += 64) {
        float4 a = gh4[c], b = ot4[c];
        ax += a.x * b.x; ay += a.y * b.y; az += a.z * b.z; aw += a.w * b.w;
      }
      for (int e = (nchunk << 2) + lane; e < n; e += 64)
        ax += gh[e] * oth[e];
    }
    outj = 32 + wave;
  }

  float v = (ax + ay) + (az + aw);
#pragma unroll
  for (int off = 32; off > 0; off >>= 1) v += __shfl_down(v, off);
  if (lane == 0 && outj >= 0)
    partials[(size_t)outj * ngrp + grp] = v;  // [RED_VALS][ngrp] column-major
}

// Stage 2: 34 blocks, block j sums partials[j][0..ngrp) (contiguous,
// coalesced) -> sums[j].
__global__ __launch_bounds__(256) void lbfgs_stage2(
    const float* __restrict__ partials, int nblk, float* __restrict__ sums) {
  const int j = blockIdx.x;
  float v = 0.f;
  for (int b = threadIdx.x; b < nblk; b += 256)
    v += partials[(size_t)j * nblk + b];
#pragma unroll
  for (int off = 32; off > 0; off >>= 1) v += __shfl_down(v, off);
  __shared__ float red[4];
  const int wave = threadIdx.x >> 6, lane = threadIdx.x & 63;
  if (lane == 0) red[wave] = v;
  __syncthreads();
  if (threadIdx.x == 0)
    sums[j] = red[0] + red[1] + red[2] + red[3];
}

__global__ __launch_bounds__(256) void lbfgs_solve(
    const float* __restrict__ sums_g,
    const float* __restrict__ Lmat, const float* __restrict__ diag,
    const float* __restrict__ sinner, const int* __restrict__ idxp,
    float* __restrict__ coeff) {
  __shared__ float sums[RED_VALS];
  if (threadIdx.x < RED_VALS) sums[threadIdx.x] = sums_g[threadIdx.x];
  __syncthreads();

  __shared__ float Lsh[HH][HH];
  __shared__ float dd[HH], sqd[HH];
  __shared__ float Jsq[HH][HH];
  __shared__ float gamma_s;
  __shared__ float x[2 * HH];
  {
    int i = threadIdx.x >> 4, j = threadIdx.x & 15;
    if (threadIdx.x < 256) Lsh[i][j] = Lmat[i * HH + j];
  }
  if (threadIdx.x < HH) {
    float dv = diag[threadIdx.x];
    float ddv = (dv == 0.f) ? 1.f : dv;
    dd[threadIdx.x] = ddv;
    sqd[threadIdx.x] = sqrtf(ddv);
  }
  if (threadIdx.x == 0) {
    float cur = sums[32], gg = sums[33];
    gamma_s = (cur > 0.f) ? (gg / cur) : 1.f;
  }
  __syncthreads();
  {
    int i = threadIdx.x >> 4, j = threadIdx.x & 15;
    float v = gamma_s * sinner[i * HH + j];
#pragma unroll
    for (int k = 0; k < HH; ++k) v += Lsh[i][k] * Lsh[j][k] / dd[k];
    Jsq[i][j] = v;
  }
  __syncthreads();
  if (threadIdx.x == 0) {
    // in-place lower Cholesky of Jsq (16x16, serial — tiny)
    for (int c = 0; c < HH; ++c) {
      float s = Jsq[c][c];
      for (int k = 0; k < c; ++k) s -= Jsq[c][k] * Jsq[c][k];
      float dv = sqrtf(s);
      Jsq[c][c] = dv;
      float inv = 1.f / dv;
      for (int r = c + 1; r < HH; ++r) {
        float s2 = Jsq[r][c];
        for (int k = 0; k < c; ++k) s2 -= Jsq[r][k] * Jsq[c][k];
        Jsq[r][c] = s2 * inv;
      }
    }
    const int is = idxp[0];
    const int sh = (is <= HH) ? 0 : (is % HH);
    const float gamma = gamma_s;
    // build rolled descent vector
    for (int k = 0; k < HH; ++k) {
      x[k]      = sums[(k + sh) & (HH - 1)];
      x[HH + k] = gamma * sums[HH + ((k + sh) & (HH - 1))];
    }
    // forward solve: low_tri = [[diag(sqd), 0], [-L/sqd_col, J]]
    for (int i = 0; i < HH; ++i) x[i] /= sqd[i];
    for (int i = 0; i < HH; ++i) {
      float s = x[HH + i];
      for (int j = 0; j < HH; ++j) s += (Lsh[i][j] / sqd[j]) * x[j];
      for (int j = 0; j < i; ++j) s -= Jsq[i][j] * x[HH + j];
      x[HH + i] = s / Jsq[i][i];
    }
    // backward solve: upper = low^T with top h rows negated
    for (int i = HH - 1; i >= 0; --i) {
      float s = x[HH + i];
      for (int j = i + 1; j < HH; ++j) s -= Jsq[j][i] * x[HH + j];
      x[HH + i] = s / Jsq[i][i];
    }
    for (int i = 0; i < HH; ++i) {
      float s = x[i];
      for (int j = 0; j < HH; ++j) s -= (Lsh[j][i] / sqd[i]) * x[HH + j];
      x[i] = s / (-sqd[i]);
    }
    // un-roll and emit coefficients (beta pre-scaled by gamma)
    coeff[0] = gamma;
    for (int k = 0; k < HH; ++k) {
      coeff[1 + k]      = x[(k - sh + HH) & (HH - 1)];
      coeff[1 + HH + k] = gamma * x[HH + ((k - sh + HH) & (HH - 1))];
    }
  }
}

// Plain ascending grid-stride (proven fastest streaming form).
__global__ __launch_bounds__(256) void lbfgs_output(
    const float* __restrict__ p, const float* __restrict__ y,
    const float* __restrict__ g, const float* __restrict__ coeff,
    float* __restrict__ out, int n) {
  const float gamma = coeff[0];
  float a[HH], b[HH];
#pragma unroll
  for (int i = 0; i < HH; ++i) {
    a[i] = coeff[1 + i];
    b[i] = coeff[1 + HH + i];
  }
  const int tid = blockIdx.x * blockDim.x + threadIdx.x;
  const int nth = gridDim.x * blockDim.x;
  const int nchunk = n >> 2;
  const float4* __restrict__ p4 = reinterpret_cast<const float4*>(p);
  float4* __restrict__ out4 = reinterpret_cast<float4*>(out);
  for (int c = tid; c < nchunk; c += nth) {
    float4 pv = p4[c];
    float ox = gamma * pv.x, oy = gamma * pv.y;
    float oz = gamma * pv.z, ow = gamma * pv.w;
#pragma unroll
    for (int i = 0; i < HH; ++i) {
      const float4 gv = reinterpret_cast<const float4*>(g + (size_t)i * n)[c];
      const float4 yv = reinterpret_cast<const float4*>(y + (size_t)i * n)[c];
      ox -= a[i] * gv.x + b[i] * yv.x;
      oy -= a[i] * gv.y + b[i] * yv.y;
      oz -= a[i] * gv.z + b[i] * yv.z;
      ow -= a[i] * gv.w + b[i] * yv.w;
    }
    out4[c] = make_float4(ox, oy, oz, ow);
  }
  for (int c = (nchunk << 2) + tid; c < n; c += nth) {
    float pv = p[c];
    float o = gamma * pv;
#pragma unroll
    for (int i = 0; i < HH; ++i)
      o -= a[i] * g[(size_t)i * n + c] + b[i] * y[(size_t)i * n + c];
    out[c] = o;
  }
}

extern "C" void kernel_launch(void* const* d_in, const int* in_sizes, int n_in,
                              void* d_out, int out_size, void* d_ws, size_t ws_size,
                              hipStream_t stream) {
  const float* p      = (const float*)d_in[0];
  const float* y      = (const float*)d_in[1];
  const float* g      = (const float*)d_in[2];
  const float* Lmat   = (const float*)d_in[3];
  const float* diag   = (const float*)d_in[4];
  const float* sinner = (const float*)d_in[5];
  const int*   idxp   = (const int*)d_in[6];
  float* out = (float*)d_out;
  float* wsf = (float*)d_ws;
  const int n = in_sizes[0];

  const int nchunk = n >> 2;
  const int nq = nchunk >> 8;             // full 256-chunk quads
  int ngrp = nq > 0 ? nq : 1;             // one quad per wave when possible
  {
    long avail = (long)(ws_size / sizeof(float)) - RED_VALS - 64;
    long cap = avail / RED_VALS;
    if (cap < 1) cap = 1;
    if (ngrp > cap) ngrp = (int)cap;      // waves loop if ws-limited
  }
  float* partials = wsf;
  float* sums     = wsf + (size_t)RED_VALS * ngrp;
  float* coeff    = sums + RED_VALS;

  lbfgs_reduce_tlp4<<<dim3(ngrp, 9), dim3(256), 0, stream>>>(
      p, y, g, idxp, partials, ngrp, n);
  lbfgs_stage2<<<dim3(RED_VALS), dim3(256), 0, stream>>>(partials, ngrp, sums);
  lbfgs_solve<<<dim3(1), dim3(256), 0, stream>>>(sums, Lmat, diag,
                                                 sinner, idxp, coeff);
  lbfgs_output<<<dim3(OUTBLK), dim3(256), 0, stream>>>(p, y, g, coeff, out, n);
}